// Round 6
// baseline (321.498 us; speedup 1.0000x reference)
//
#include <hip/hip_runtime.h>

typedef __bf16 bf16;
typedef __bf16 bf16x4 __attribute__((ext_vector_type(4)));
typedef __bf16 bf16x8 __attribute__((ext_vector_type(8)));
typedef float  f32x4  __attribute__((ext_vector_type(4)));

#define TOKENS 16384
#define D_IN   4096
#define D_OUT  4096
#define RANK   512

// Async global->LDS, 16B per lane. LDS dest must be wave-uniform base + lane*16.
__device__ inline void gload_lds16(const bf16* g, bf16* l) {
    __builtin_amdgcn_global_load_lds((const __attribute__((address_space(1))) void*)g,
                                     (__attribute__((address_space(3))) void*)l,
                                     16, 0, 0);
}

// ---------------------------------------------------------------------------
// Prep 1: Vst[r][k'] = bf16(V[k][r] * sigma[r]), PRE-SWIZZLED (verified r3/r4:
//   conflicts -> 0). Within each 64-k block: k -> k ^ ((r&7)<<3).
//   Split-K at k=2048 is a 64-block boundary, so the swizzle is unaffected.
// ---------------------------------------------------------------------------
__global__ __launch_bounds__(256) void vt_scale(const float* __restrict__ V,
                                                const float* __restrict__ sg,
                                                bf16* __restrict__ Vst) {
    __shared__ float tile[64][65];
    const int tx = threadIdx.x & 63;
    const int ty = threadIdx.x >> 6;
    const int kb = blockIdx.x * 64;
    const int rb = blockIdx.y * 64;
    const float s = sg[rb + tx];
#pragma unroll
    for (int i = ty; i < 64; i += 4)
        tile[i][tx] = V[(size_t)(kb + i) * RANK + rb + tx] * s;
    __syncthreads();
#pragma unroll
    for (int i = ty; i < 64; i += 4) {
        int r = rb + i;
        int kp = kb + (tx ^ ((r & 7) << 3));
        Vst[(size_t)r * D_IN + kp] = (bf16)tile[tx][i];
    }
}

// ---------------------------------------------------------------------------
// Prep 2: elementwise f32 -> bf16
// ---------------------------------------------------------------------------
__global__ __launch_bounds__(256) void cvt_bf16_4(const float* __restrict__ in,
                                                  bf16* __restrict__ o, int n4) {
    int i = blockIdx.x * 256 + threadIdx.x;
    if (i < n4) {
        f32x4 v = *(const f32x4*)(in + (size_t)i * 4);
        bf16x4 b = { (bf16)v[0], (bf16)v[1], (bf16)v[2], (bf16)v[3] };
        *(bf16x4*)(o + (size_t)i * 4) = b;
    }
}

// ---------------------------------------------------------------------------
// GEMM1 SPLIT-K=2: P[kh] = A_f32[:, kh*2048:+2048] @ B^T[.., same k range]
//   r4's single-buffer 32KB structure (fastest measured; swizzled, conflict
//   free), grid 1024 = 2 k-halves x 512 tiles -> 4 blocks/CU (the occupancy
//   experiment, unconfounded: per-K-step MFMA density unchanged).
// ---------------------------------------------------------------------------
__global__ __launch_bounds__(256) void gemm1_sk(const float* __restrict__ A,
                                                const bf16* __restrict__ B,
                                                float* __restrict__ P,
                                                int M, int N, int Kfull, int Khalf) {
    __shared__ bf16 Al[128 * 64];
    __shared__ bf16 Bl[128 * 64];

    const int t  = threadIdx.x;
    const int l  = t & 63;
    const int w  = t >> 6;
    const int wr = w >> 1, wc = w & 1;
    const int lr = l & 15;
    const int kg = l >> 4;
    const int sxor = (lr & 7) << 3;

    // XCD-aware bijective swizzle (nwg=1024, %8==0); khalf is the high bit of
    // swz so each XCD still walks contiguous tiles within one k-half.
    const int nwg = gridDim.x;
    const int bid = blockIdx.x;
    const int cpx = nwg >> 3;
    const int swz = (bid & 7) * cpx + (bid >> 3);
    const int khalf  = swz >> 9;          // 0 or 1
    const int tileid = swz & 511;
    const int ntn = N >> 7;               // 4
    const int tm  = (tileid / ntn) << 7;
    const int tn  = (tileid % ntn) << 7;
    const int kbase = khalf * Khalf;

    const int arow  = t >> 4;
    const int acg   = t & 15;
    const int awxor = (arow & 7) << 3;
    const float* Ap = A + (size_t)(tm + arow) * Kfull + kbase + acg * 4;
    const bf16* Bp  = B + (size_t)(tn + (t >> 3)) * Kfull + kbase + (t & 7) * 8;

    f32x4 acc[4][4] = {};

    for (int kt = 0; kt < Khalf; kt += 64) {
        // ---- B tile via async DMA first (overlaps A's reg round-trip) ----
#pragma unroll
        for (int c = 0; c < 4; ++c)
            gload_lds16(Bp + kt + (size_t)(c * 32) * Kfull, &Bl[(c * 256 + t) * 8]);
        // ---- A tile: f32 load -> bf16 cvt -> swizzled ds_write ----
        f32x4 ra[8];
#pragma unroll
        for (int c = 0; c < 8; ++c)
            ra[c] = *(const f32x4*)(Ap + kt + (size_t)(c * 16) * Kfull);
#pragma unroll
        for (int c = 0; c < 8; ++c) {
            bf16x4 b = { (bf16)ra[c][0], (bf16)ra[c][1], (bf16)ra[c][2], (bf16)ra[c][3] };
            *(bf16x4*)&Al[(c * 16 + arow) * 64 + ((acg * 4) ^ awxor)] = b;
        }
        __syncthreads();

#pragma unroll
        for (int ks = 0; ks < 2; ++ks) {
            bf16x8 af[4], bfr[4];
#pragma unroll
            for (int f = 0; f < 4; ++f) {
                af[f]  = *(const bf16x8*)&Al[(wr * 64 + f * 16 + lr) * 64 + ((ks * 32 + kg * 8) ^ sxor)];
                bfr[f] = *(const bf16x8*)&Bl[(wc * 64 + f * 16 + lr) * 64 + ((ks * 32 + kg * 8) ^ sxor)];
            }
#pragma unroll
            for (int fm = 0; fm < 4; ++fm)
#pragma unroll
                for (int fn = 0; fn < 4; ++fn)
                    acc[fm][fn] = __builtin_amdgcn_mfma_f32_16x16x32_bf16(
                        af[fm], bfr[fn], acc[fm][fn], 0, 0, 0);
        }
        __syncthreads();
    }

    // ---- f32 partial write: col = lane&15, row = (lane>>4)*4 + reg ----
    float* Po = P + (size_t)khalf * M * N;
    const int r0 = tm + wr * 64 + kg * 4;
    const int c0 = tn + wc * 64 + lr;
#pragma unroll
    for (int fm = 0; fm < 4; ++fm)
#pragma unroll
        for (int fn = 0; fn < 4; ++fn)
#pragma unroll
            for (int r = 0; r < 4; ++r)
                Po[(size_t)(r0 + fm * 16 + r) * N + (c0 + fn * 16)] = acc[fm][fn][r];
}

// ---------------------------------------------------------------------------
// Reduce: T = bf16(P0 + P1), 8M elements, f32x4 vectorized grid-stride.
// ---------------------------------------------------------------------------
__global__ __launch_bounds__(256) void reduce_T(const float* __restrict__ P,
                                                bf16* __restrict__ T, int n4) {
    const float* P1 = P + (size_t)TOKENS * RANK;
    int stride = gridDim.x * 256;
    for (int i = blockIdx.x * 256 + threadIdx.x; i < n4; i += stride) {
        f32x4 a = *(const f32x4*)(P  + (size_t)i * 4);
        f32x4 b = *(const f32x4*)(P1 + (size_t)i * 4);
        bf16x4 o = { (bf16)(a[0] + b[0]), (bf16)(a[1] + b[1]),
                     (bf16)(a[2] + b[2]), (bf16)(a[3] + b[3]) };
        *(bf16x4*)(T + (size_t)i * 4) = o;
    }
}

// ---------------------------------------------------------------------------
// GEMM2 (r4 control, unchanged): C_f32 = A_bf16 @ B_bf16^T, 128x128, 32KB LDS.
// ---------------------------------------------------------------------------
__global__ __launch_bounds__(256) void gemm2_bt(const bf16* __restrict__ A,
                                                const bf16* __restrict__ B,
                                                float* __restrict__ out,
                                                int M, int N, int K) {
    __shared__ bf16 Al[128 * 64];
    __shared__ bf16 Bl[128 * 64];

    const int t  = threadIdx.x;
    const int l  = t & 63;
    const int w  = t >> 6;
    const int wr = w >> 1, wc = w & 1;
    const int lr = l & 15;
    const int kg = l >> 4;

    const int nwg = gridDim.x;
    const int bid = blockIdx.x;
    const int cpx = nwg >> 3;
    const int swz = (bid & 7) * cpx + (bid >> 3);
    const int ntn = N >> 7;
    const int tm  = (swz / ntn) << 7;
    const int tn  = (swz % ntn) << 7;

    f32x4 acc[4][4] = {};

    for (int kt = 0; kt < K; kt += 64) {
#pragma unroll
        for (int c = 0; c < 4; ++c) {
            int i = c * 256 + t;
            gload_lds16(A + (size_t)(tm + (i >> 3)) * K + kt + (i & 7) * 8, &Al[i * 8]);
        }
#pragma unroll
        for (int c = 0; c < 4; ++c) {
            int i = c * 256 + t;
            gload_lds16(B + (size_t)(tn + (i >> 3)) * K + kt + (i & 7) * 8, &Bl[i * 8]);
        }
        __syncthreads();

#pragma unroll
        for (int ks = 0; ks < 2; ++ks) {
            bf16x8 af[4], bfr[4];
#pragma unroll
            for (int f = 0; f < 4; ++f) {
                af[f]  = *(const bf16x8*)&Al[(wr * 64 + f * 16 + lr) * 64 + ks * 32 + kg * 8];
                bfr[f] = *(const bf16x8*)&Bl[(wc * 64 + f * 16 + lr) * 64 + ks * 32 + kg * 8];
            }
#pragma unroll
            for (int fm = 0; fm < 4; ++fm)
#pragma unroll
                for (int fn = 0; fn < 4; ++fn)
                    acc[fm][fn] = __builtin_amdgcn_mfma_f32_16x16x32_bf16(
                        af[fm], bfr[fn], acc[fm][fn], 0, 0, 0);
        }
        __syncthreads();
    }

    const int r0 = tm + wr * 64 + kg * 4;
    const int c0 = tn + wc * 64 + lr;
#pragma unroll
    for (int fm = 0; fm < 4; ++fm)
#pragma unroll
        for (int fn = 0; fn < 4; ++fn)
#pragma unroll
            for (int r = 0; r < 4; ++r)
                out[(size_t)(r0 + fm * 16 + r) * N + (c0 + fn * 16)] = acc[fm][fn][r];
}

// ---------------------------------------------------------------------------
extern "C" void kernel_launch(void* const* d_in, const int* in_sizes, int n_in,
                              void* d_out, int out_size, void* d_ws, size_t ws_size,
                              hipStream_t stream) {
    const float* x  = (const float*)d_in[0];  // [16384][4096]
    const float* U  = (const float*)d_in[1];  // [4096][512]
    const float* sg = (const float*)d_in[2];  // [512]
    const float* V  = (const float*)d_in[3];  // [4096][512]
    float* out = (float*)d_out;               // [16384][4096] f32

    char* ws = (char*)d_ws;
    bf16*  Vst = (bf16*)ws;                    // [512][4096]   = 4 MB (pre-swizzled)
    bf16*  Ub  = (bf16*)(ws + (4u << 20));     // [4096][512]   = 4 MB
    bf16*  T   = (bf16*)(ws + (8u << 20));     // [16384][512]  = 16 MB
    float* Pf  = (float*)(ws + (32u << 20));   // 2x[16384][512] f32 = 64 MB

    vt_scale<<<dim3(D_IN / 64, RANK / 64), 256, 0, stream>>>(V, sg, Vst);
    cvt_bf16_4<<<(D_OUT * RANK / 4 + 255) / 256, 256, 0, stream>>>(U, Ub, D_OUT * RANK / 4);

    // GEMM1 split-K=2: grid 1024 blocks (4/CU), each K=2048
    gemm1_sk<<<2 * (TOKENS / 128) * (RANK / 128), 256, 0, stream>>>(
        x, Vst, Pf, TOKENS, RANK, D_IN, D_IN / 2);

    // T = bf16(P0 + P1)
    reduce_T<<<2048, 256, 0, stream>>>(Pf, T, TOKENS * RANK / 4);

    // GEMM2: out = T @ Ub^T (f32 out), grid 4096 blocks
    gemm2_bt<<<(TOKENS / 128) * (D_OUT / 128), 256, 0, stream>>>(
        T, Ub, out, TOKENS, D_OUT, RANK);
}